// Round 4
// baseline (326.593 us; speedup 1.0000x reference)
//
#include <hip/hip_runtime.h>

typedef unsigned short u16;
typedef __attribute__((ext_vector_type(8))) short v8s;   // 8 bf16 = 4 VGPRs
typedef __attribute__((ext_vector_type(4))) float v4f;   // MFMA accumulator
typedef __attribute__((ext_vector_type(4))) float f4;

#define HID 128
#define TM  64          // edges per tile
#define SEF_S 260       // u16 stride: par|cld -> encP|encC (256 + 4)
#define SD_S  132       // u16 stride: diff buffer (128 + 4)
#define SH_S  132       // u16 stride: H buffer (128 + 4)
#define NBLK  512       // persistent blocks: 2 per CU

__device__ __forceinline__ u16 f2b(float f) {            // fp32 -> bf16 RNE
    union { float f; unsigned u; } v; v.f = f;
    unsigned u = v.u;
    u += 0x7fffu + ((u >> 16) & 1u);
    return (u16)(u >> 16);
}

#define MFMA(A, B, C) __builtin_amdgcn_mfma_f32_16x16x32_bf16(A, B, C, 0, 0, 0)

// ---- weight fp32 -> bf16 pre-pass (once per launch, ~0.2 MB total) ----
// ws layout (u16 elems): Wp @0 (16384) | Wc @16384 | W1 @32768 (49152) | W2 @81920
__global__ void cvt_weights(const float* __restrict__ Wp, const float* __restrict__ Wc,
                            const float* __restrict__ W1, const float* __restrict__ W2,
                            u16* __restrict__ dst)
{
    int i = blockIdx.x * 256 + threadIdx.x;   // float4 index, 24576 total
    const float* s; int off;
    if (i < 4096)       { s = Wp; off = 0; }
    else if (i < 8192)  { s = Wc; off = 4096; }
    else if (i < 20480) { s = W1; off = 8192; }
    else                { s = W2; off = 20480; }
    int j = i - off;
    f4 v = ((const f4*)s)[j];
    u16* d = dst + (size_t)i * 4;
    d[0] = f2b(v[0]); d[1] = f2b(v[1]); d[2] = f2b(v[2]); d[3] = f2b(v[3]);
}

// issue the 16 row-gather float4 loads for a tile (raw fp32 kept in registers)
__device__ __forceinline__ void gather_issue(const float* __restrict__ xs,
                                             const float* __restrict__ xd,
                                             int pI, int cI, int t,
                                             f4* rp0, f4* rp1, f4* rq0, f4* rq1)
{
    const int cg = (t & 15) << 3;            // 8-float column chunk
    #pragma unroll
    for (int i = 0; i < 4; ++i) {
        int r = (t >> 4) + i * 16;           // row 0..63, each exactly once per block
        int pi = __shfl(pI, r);
        int ci = __shfl(cI, r);
        const f4* ps = (const f4*)(xs + (size_t)pi * HID + cg);
        const f4* qs = (const f4*)(xd + (size_t)ci * HID + cg);
        rp0[i] = ps[0]; rp1[i] = ps[1];
        rq0[i] = qs[0]; rq1[i] = qs[1];
    }
}

// convert + store a gathered tile into sEF (par|cld) and sD (diff)
__device__ __forceinline__ void gather_store(int t,
                                             const f4* rp0, const f4* rp1,
                                             const f4* rq0, const f4* rq1,
                                             u16* sEF, u16* sD)
{
    const int cg = (t & 15) << 3;
    #pragma unroll
    for (int i = 0; i < 4; ++i) {
        int r = (t >> 4) + i * 16;
        f4 p0 = rp0[i], p1 = rp1[i], q0 = rq0[i], q1 = rq1[i];
        v8s pb, qb, db;
        #pragma unroll
        for (int j = 0; j < 4; ++j) {
            pb[j]     = (short)f2b(p0[j]);
            pb[j + 4] = (short)f2b(p1[j]);
            qb[j]     = (short)f2b(q0[j]);
            qb[j + 4] = (short)f2b(q1[j]);
            db[j]     = (short)f2b(fabsf(p0[j] - q0[j]));
            db[j + 4] = (short)f2b(fabsf(p1[j] - q1[j]));
        }
        *(v8s*)&sEF[r * SEF_S       + cg] = pb;
        *(v8s*)&sEF[r * SEF_S + 128 + cg] = qb;
        *(v8s*)&sD [r * SD_S        + cg] = db;
    }
}

__global__ __launch_bounds__(256, 2) void edge_attr_kernel(
    const float* __restrict__ x_src, const float* __restrict__ x_dst,
    const int* __restrict__ ei,
    const u16* __restrict__ wsW,                 // converted weights in d_ws
    const float* __restrict__ bp, const float* __restrict__ bc,
    const float* __restrict__ b1, const float* __restrict__ b2,
    float* __restrict__ out, int E)
{
    __shared__ __align__(16) u16 sEF[TM * SEF_S];  // 33280 B: par|cld -> encP|encC
    __shared__ __align__(16) u16 sD [TM * SD_S];   // 16896 B: diff
    __shared__ __align__(16) u16 sH [TM * SH_S];   // 16896 B: H

    const u16* wsWp = wsW;
    const u16* wsWc = wsW + 16384;
    const u16* wsW1 = wsW + 32768;
    const u16* wsW2 = wsW + 81920;

    const int t  = threadIdx.x;
    const int l  = t & 63;
    const int ln = l & 15;          // C-col / A-row within 16-tile
    const int lq = l >> 4;          // quad: k-base lq*8; C-row base lq*4
    const int n0 = (t >> 6) * 32;   // wave's output-column slice
    const int nT = (E + TM - 1) / TM;
    const int stride = gridDim.x;

    // ---- persistent, loop-invariant stage-1/3 weights & biases (register-resident) ----
    v8s Bp[2][4], Bc[2][4];
    float bpv[2], bcv[2], b1v[2], b2v[2];
    #pragma unroll
    for (int nt = 0; nt < 2; ++nt) {
        int n = n0 + nt * 16 + ln;
        bpv[nt] = bp[n];  bcv[nt] = bc[n];
        b1v[nt] = b1[n];  b2v[nt] = b2[n];
        #pragma unroll
        for (int kt = 0; kt < 4; ++kt) {
            Bp[nt][kt] = *(const v8s*)(wsWp + (size_t)n * HID + kt * 32 + lq * 8);
            Bc[nt][kt] = *(const v8s*)(wsWc + (size_t)n * HID + kt * 32 + lq * 8);
        }
    }

    // ---- prologue: gather tile = blockIdx.x into LDS ----
    int tile = blockIdx.x;
    if (tile >= nT) return;
    {
        int eg = tile * TM + l; if (eg >= E) eg = E - 1;
        int pI = ei[eg], cI = ei[E + eg];
        f4 a0[4], a1[4], c0[4], c1[4];
        gather_issue(x_src, x_dst, pI, cI, t, a0, a1, c0, c1);
        gather_store(t, a0, a1, c0, c1, sEF, sD);
    }
    __syncthreads();   // B0: tile-0 data visible

    for (;;) {
        const int e0 = tile * TM;
        const int nextTile = tile + stride;
        const bool hasNext = nextTile < nT;
        const int pTile = hasNext ? nextTile : tile;   // clamped: harmless dummy prefetch

        // ---- next-tile index loads (in flight under stage 1) ----
        int egN = pTile * TM + l; if (egN >= E) egN = E - 1;
        int pIN = ei[egN];
        int cIN = ei[E + egN];

        // ---------------- stage 1: enc_p / enc_c (K=128) ----------------
        v4f aP[4][2], aC[4][2];
        #pragma unroll
        for (int mt = 0; mt < 4; ++mt)
            #pragma unroll
            for (int nt = 0; nt < 2; ++nt) {
                aP[mt][nt] = (v4f){0.f, 0.f, 0.f, 0.f};
                aC[mt][nt] = (v4f){0.f, 0.f, 0.f, 0.f};
            }
        #pragma unroll
        for (int mt = 0; mt < 4; ++mt) {
            const int rbase = (mt * 16 + ln) * SEF_S + lq * 8;
            v8s A[4];
            #pragma unroll
            for (int kt = 0; kt < 4; ++kt) A[kt] = *(const v8s*)&sEF[rbase + kt * 32];
            #pragma unroll
            for (int nt = 0; nt < 2; ++nt)
                #pragma unroll
                for (int kt = 0; kt < 4; ++kt) aP[mt][nt] = MFMA(A[kt], Bp[nt][kt], aP[mt][nt]);
            #pragma unroll
            for (int kt = 0; kt < 4; ++kt) A[kt] = *(const v8s*)&sEF[rbase + 128 + kt * 32];
            #pragma unroll
            for (int nt = 0; nt < 2; ++nt)
                #pragma unroll
                for (int kt = 0; kt < 4; ++kt) aC[mt][nt] = MFMA(A[kt], Bc[nt][kt], aC[mt][nt]);
        }
        __syncthreads();   // B1: all waves done reading par/cld
        #pragma unroll
        for (int mt = 0; mt < 4; ++mt)
            #pragma unroll
            for (int nt = 0; nt < 2; ++nt)
                #pragma unroll
                for (int rg = 0; rg < 4; ++rg) {
                    int row = mt * 16 + lq * 4 + rg;
                    int col = n0 + nt * 16 + ln;
                    float vp = aP[mt][nt][rg] + bpv[nt];
                    vp = vp > 0.f ? vp : 0.01f * vp;
                    sEF[row * SEF_S + col] = f2b(vp);
                    float vc = aC[mt][nt][rg] + bcv[nt];
                    vc = vc > 0.f ? vc : 0.01f * vc;
                    sEF[row * SEF_S + 128 + col] = f2b(vc);
                }
        __syncthreads();   // B2: enc visible

        // ---- next-tile row gathers: in flight under the whole stage-2 K-loop ----
        f4 rp0[4], rp1[4], rq0[4], rq1[4];
        gather_issue(x_src, x_dst, pIN, cIN, t, rp0, rp1, rq0, rq1);

        // ---------------- stage 2: H = relu([encP|encC|diff] @ W1^T + b1) ----------------
        v4f acc2[4][2];
        #pragma unroll
        for (int mt = 0; mt < 4; ++mt)
            #pragma unroll
            for (int nt = 0; nt < 2; ++nt) acc2[mt][nt] = (v4f){0.f, 0.f, 0.f, 0.f};
        #pragma unroll
        for (int ktc = 0; ktc < 3; ++ktc) {          // K chunks: encP | encC | diff
            v8s B[2][4];
            #pragma unroll
            for (int nt = 0; nt < 2; ++nt) {
                int n = n0 + nt * 16 + ln;
                #pragma unroll
                for (int k4 = 0; k4 < 4; ++k4)
                    B[nt][k4] = *(const v8s*)(wsW1 + (size_t)n * 384 + ktc * 128 + k4 * 32 + lq * 8);
            }
            const u16* Asrc = (ktc < 2) ? (sEF + ktc * 128) : sD;
            const int  Astr = (ktc < 2) ? SEF_S : SD_S;
            #pragma unroll
            for (int mt = 0; mt < 4; ++mt) {
                const int rbase = (mt * 16 + ln) * Astr + lq * 8;
                v8s A[4];
                #pragma unroll
                for (int k4 = 0; k4 < 4; ++k4) A[k4] = *(const v8s*)&Asrc[rbase + k4 * 32];
                #pragma unroll
                for (int nt = 0; nt < 2; ++nt)
                    #pragma unroll
                    for (int k4 = 0; k4 < 4; ++k4) acc2[mt][nt] = MFMA(A[k4], B[nt][k4], acc2[mt][nt]);
            }
        }
        __syncthreads();   // B3: all reads of sEF(enc) and sD(diff) retired

        // store prefetched tile into sEF/sD (overwrites enc/diff; safe after B3)
        gather_store(t, rp0, rp1, rq0, rq1, sEF, sD);

        // stage-2 epilogue: H -> sH (sH free since B1 retired stage-3 reads of prev tile)
        #pragma unroll
        for (int mt = 0; mt < 4; ++mt)
            #pragma unroll
            for (int nt = 0; nt < 2; ++nt)
                #pragma unroll
                for (int rg = 0; rg < 4; ++rg) {
                    int row = mt * 16 + lq * 4 + rg;
                    int col = n0 + nt * 16 + ln;
                    float v = acc2[mt][nt][rg] + b1v[nt];
                    sH[row * SH_S + col] = f2b(fmaxf(v, 0.f));
                }
        __syncthreads();   // B4: H + next-tile gather visible

        // ---------------- stage 3: out = H @ W2^T + b2, direct store ----------------
        {
            v8s B2[2][4];
            #pragma unroll
            for (int nt = 0; nt < 2; ++nt) {
                int n = n0 + nt * 16 + ln;
                #pragma unroll
                for (int kt = 0; kt < 4; ++kt)
                    B2[nt][kt] = *(const v8s*)(wsW2 + (size_t)n * HID + kt * 32 + lq * 8);
            }
            v4f acc3[4][2];
            #pragma unroll
            for (int mt = 0; mt < 4; ++mt)
                #pragma unroll
                for (int nt = 0; nt < 2; ++nt) acc3[mt][nt] = (v4f){0.f, 0.f, 0.f, 0.f};
            #pragma unroll
            for (int mt = 0; mt < 4; ++mt) {
                const int rbase = (mt * 16 + ln) * SH_S + lq * 8;
                v8s A[4];
                #pragma unroll
                for (int kt = 0; kt < 4; ++kt) A[kt] = *(const v8s*)&sH[rbase + kt * 32];
                #pragma unroll
                for (int nt = 0; nt < 2; ++nt)
                    #pragma unroll
                    for (int kt = 0; kt < 4; ++kt) acc3[mt][nt] = MFMA(A[kt], B2[nt][kt], acc3[mt][nt]);
            }
            // direct C-layout stores: 16 consecutive lanes -> 64B contiguous segments
            #pragma unroll
            for (int mt = 0; mt < 4; ++mt)
                #pragma unroll
                for (int nt = 0; nt < 2; ++nt)
                    #pragma unroll
                    for (int rg = 0; rg < 4; ++rg) {
                        int row = mt * 16 + lq * 4 + rg;
                        int e = e0 + row;
                        if (e < E)
                            out[(size_t)e * HID + n0 + nt * 16 + ln] = acc3[mt][nt][rg] + b2v[nt];
                    }
        }
        // stage 3 of tile j overlaps stage 1 of tile j+1 (no loop-top barrier needed:
        // B1 protects the sEF overwrite, B3 protects the sH overwrite)
        if (!hasNext) break;
        tile = nextTile;
    }
}

extern "C" void kernel_launch(void* const* d_in, const int* in_sizes, int n_in,
                              void* d_out, int out_size, void* d_ws, size_t ws_size,
                              hipStream_t stream) {
    const float* x_src = (const float*)d_in[0];
    const float* x_dst = (const float*)d_in[1];
    const int*   ei    = (const int*)d_in[2];
    const float* Wp    = (const float*)d_in[3];
    const float* bp    = (const float*)d_in[4];
    const float* Wc    = (const float*)d_in[5];
    const float* bc    = (const float*)d_in[6];
    const float* W1    = (const float*)d_in[7];
    const float* b1    = (const float*)d_in[8];
    const float* W2    = (const float*)d_in[9];
    const float* b2    = (const float*)d_in[10];
    float* out = (float*)d_out;
    u16* wsW = (u16*)d_ws;                    // 98304 u16 = 196608 B

    int E = in_sizes[2] / 2;                  // edge_index is [2, E]
    int nT = (E + TM - 1) / TM;
    int blocks = nT < NBLK ? nT : NBLK;

    cvt_weights<<<96, 256, 0, stream>>>(Wp, Wc, W1, W2, wsW);

    edge_attr_kernel<<<blocks, 256, 0, stream>>>(
        x_src, x_dst, ei, wsW, bp, bc, b1, b2, out, E);
}